// Round 1
// baseline (345.533 us; speedup 1.0000x reference)
//
#include <hip/hip_runtime.h>

// HOGCN: 2-layer GraphConv, N=50000, D=64, E=1.6M, fp32.
// Round 16 = round 15 (197us) + ONE structural change: node-granular
// counting sort, eliminating sort_kernel + colscan_kernel entirely.
//   Old build: bucket hist -> colscan -> bin(LDS cursors, 10-bit w) ->
//              sort(8MB reread, 2x LDS-atomic passes, 8MB rewrite).
//   New build: node hist (global atomics, fused w/ t1) -> 2-stage scan
//              (50K nodes) -> bin places records at FINAL position via
//              global atomicAdd cursor. epk dense (6.4MB, no PAD).
//   Aggregate kernels are UNCHANGED (same record format: src|bf16w<<16,
//   same beg/endo semantics) -- they were shown line-bound at the
//   1-line/edge floor in r12-r15, nothing left there.
//   w now full bf16 (10-bit quantization dropped; dst bits unneeded).
//   Within-node order = atomic arrival (fp32 sum reorder, negligible).
// Weights(bf16)/Z8(fp8)/Yb/Hb + transforms unchanged from round 15.

#define NN 50000
#define DD 64
#define EE 1600000
#define CHUNK 8192
#define NC ((EE + CHUNK - 1) / CHUNK)       // 196 hist chunks
#define NSB ((NN + 255) / 256)              // 196 scan blocks

static_assert(NSB <= 256, "scan_c scan width must cover all scan blocks");
static_assert(EE % 256 == 0, "bin grid is exact one-edge-per-thread");

typedef __attribute__((ext_vector_type(8))) short short8;   // 8 bf16, 4 VGPRs
typedef __attribute__((ext_vector_type(4))) float f32x4;

__device__ __forceinline__ unsigned short f2bf(float f) {   // RNE
    unsigned u = __float_as_uint(f);
    u += 0x7FFF + ((u >> 16) & 1);
    return (unsigned short)(u >> 16);
}
__device__ __forceinline__ float bflo(unsigned u) {
    return __uint_as_float(u << 16);
}
__device__ __forceinline__ float bfhi(unsigned u) {
    return __uint_as_float(u & 0xFFFF0000u);
}
__device__ __forceinline__ unsigned char f2fp8(float f) {   // e4m3, RNE
    unsigned p = __builtin_amdgcn_cvt_pk_fp8_f32(f, f, 0, false);
    return (unsigned char)(p & 0xFF);
}

// ---------- dense transform body (MFMA), shared by both layers ----------
#define XS_STR 72
#define WS_STR 72

template <typename TIn>
__device__ __forceinline__ void transform_body(
    int blk, int t,
    const TIn* __restrict__ xin,
    const float* __restrict__ Wrel, const float* __restrict__ Wroot,
    const float* __restrict__ bias,
    unsigned char* __restrict__ Z8, unsigned short* __restrict__ Yb,
    unsigned short* Xs, unsigned short* Ws)
{
    const int node0 = blk * 64;

    // stage Wcat: 2048 float4s, 8 per thread
#pragma unroll
    for (int i = 0; i < 8; ++i) {
        int flat = i * 256 + t;              // float4 index 0..2047
        int row  = flat >> 4;                // 0..127
        int c4   = flat & 15;
        const float* src = (row < 64 ? Wrel + row * 64
                                     : Wroot + (row - 64) * 64) + c4 * 4;
        float4 v = *(const float4*)src;
        unsigned short* d = &Ws[row * WS_STR + c4 * 4];
        d[0] = f2bf(v.x); d[1] = f2bf(v.y); d[2] = f2bf(v.z); d[3] = f2bf(v.w);
    }
    // stage X tile (zero-pad past NN)
    if constexpr (sizeof(TIn) == 4) {        // fp32 input
#pragma unroll
        for (int i = 0; i < 4; ++i) {
            int flat = i * 256 + t;          // 0..1023 float4s
            int row  = flat >> 4;
            int c4   = flat & 15;
            int node = node0 + row;
            float4 v = make_float4(0.f, 0.f, 0.f, 0.f);
            if (node < NN) v = *(const float4*)((const float*)xin + (size_t)node * 64 + c4 * 4);
            unsigned short* d = &Xs[row * XS_STR + c4 * 4];
            d[0] = f2bf(v.x); d[1] = f2bf(v.y); d[2] = f2bf(v.z); d[3] = f2bf(v.w);
        }
    } else {                                 // bf16 input (Hb)
#pragma unroll
        for (int i = 0; i < 2; ++i) {
            int flat = i * 256 + t;          // 0..511 short8s
            int row  = flat >> 3;
            int c8   = flat & 7;
            int node = node0 + row;
            short8 v = {0,0,0,0,0,0,0,0};
            if (node < NN)
                v = *(const short8*)((const unsigned short*)xin + (size_t)node * 64 + c8 * 8);
            *(short8*)&Xs[row * XS_STR + c8 * 8] = v;
        }
    }
    __syncthreads();

    const int w    = t >> 6;                 // wave: node rows w*16..w*16+15
    const int lane = t & 63;
    const int l15  = lane & 15;
    const int quad = lane >> 4;

    short8 a0 = *(const short8*)&Xs[(w * 16 + l15) * XS_STR + quad * 8];
    short8 a1 = *(const short8*)&Xs[(w * 16 + l15) * XS_STR + 32 + quad * 8];

#pragma unroll
    for (int f = 0; f < 8; ++f) {
        short8 b0 = *(const short8*)&Ws[(f * 16 + l15) * WS_STR + quad * 8];
        short8 b1 = *(const short8*)&Ws[(f * 16 + l15) * WS_STR + 32 + quad * 8];
        f32x4 acc = {0.f, 0.f, 0.f, 0.f};
        acc = __builtin_amdgcn_mfma_f32_16x16x32_bf16(a0, b0, acc, 0, 0, 0);
        acc = __builtin_amdgcn_mfma_f32_16x16x32_bf16(a1, b1, acc, 0, 0, 0);
        const int col = f * 16 + l15;        // 0..127 in [Z | Y]
#pragma unroll
        for (int r = 0; r < 4; ++r) {        // D row = quad*4 + r
            int node = node0 + w * 16 + quad * 4 + r;
            if (node < NN) {
                if (col < 64) Z8[(size_t)node * 64 + col] = f2fp8(acc[r]);
                else          Yb[(size_t)node * 64 + (col - 64)] =
                                  f2bf(acc[r] + bias[col - 64]);
            }
        }
    }
}

// ---------- build 0: zero the per-node histogram ----------
__global__ __launch_bounds__(256) void zero_kernel(int* __restrict__ cnt)
{
    int i = blockIdx.x * 256 + threadIdx.x;
    if (i < NN) cnt[i] = 0;
}

// ---------- fused: node hist (blocks 0..NC-1) + layer-1 transform ------
__global__ __launch_bounds__(256) void hist_t1_kernel(
    const int* __restrict__ ei, int* __restrict__ cnt,
    const float* __restrict__ x,
    const float* __restrict__ Wrel, const float* __restrict__ Wroot,
    const float* __restrict__ bias,
    unsigned char* __restrict__ Z8, unsigned short* __restrict__ Yb)
{
    __shared__ unsigned short Xs[64 * XS_STR];    //  9.2 KB
    __shared__ unsigned short Ws[128 * WS_STR];   // 18.4 KB
    const int t = threadIdx.x;

    if (blockIdx.x < NC) {                   // ---- histogram chunk ----
        const int base = blockIdx.x * CHUNK;
#pragma unroll 4
        for (int i = 0; i < CHUNK; i += 256) {
            int e = base + i + t;
            if (e < EE) atomicAdd(&cnt[ei[EE + e]], 1);   // dst node
        }
    } else {                                 // ---- layer-1 transform ----
        transform_body<float>(blockIdx.x - NC, t, x, Wrel, Wroot, bias,
                              Z8, Yb, Xs, Ws);
    }
}

// ---------- build 2a: per-scanblock totals (256 nodes each) ----------
__global__ __launch_bounds__(256) void scan_a(
    const int* __restrict__ cnt, int* __restrict__ btot)
{
    __shared__ int wsum[4];
    const int b = blockIdx.x, t = threadIdx.x;
    int n = b * 256 + t;
    int v = (n < NN) ? cnt[n] : 0;
    for (int off = 1; off < 64; off <<= 1) v += __shfl_xor(v, off);
    if ((t & 63) == 0) wsum[t >> 6] = v;
    __syncthreads();
    if (t == 0) btot[b] = wsum[0] + wsum[1] + wsum[2] + wsum[3];
}

// ---------- build 2b: global exclusive scan -> beg/endo/cur ----------
// Each block redundantly scans the 196 block totals (colscan pattern),
// then scans its own 256 node counts.
__global__ __launch_bounds__(256) void scan_c(
    const int* __restrict__ cnt, const int* __restrict__ btot,
    int* __restrict__ beg, int* __restrict__ endo, int* __restrict__ cur)
{
    __shared__ int part[256];
    __shared__ int nods[256];
    const int b = blockIdx.x, t = threadIdx.x;

    int h = (t < NSB) ? btot[t] : 0;
    part[t] = h;
    __syncthreads();
    for (int off = 1; off < 256; off <<= 1) {        // Hillis-Steele incl.
        int v = (t >= off) ? part[t - off] : 0;
        __syncthreads();
        part[t] += v;
        __syncthreads();
    }
    const int P = part[b] - btot[b];         // exclusive prefix of block b

    const int n = b * 256 + t;
    const int c = (n < NN) ? cnt[n] : 0;
    nods[t] = c;
    __syncthreads();
    for (int off = 1; off < 256; off <<= 1) {
        int v = (t >= off) ? nods[t - off] : 0;
        __syncthreads();
        nods[t] += v;
        __syncthreads();
    }
    if (n < NN) {
        int bg = P + nods[t] - c;
        beg[n]  = bg;
        endo[n] = bg + c;
        cur[n]  = bg;
    }
}

// ---------- build 3: place records at FINAL sorted position ----------
// record = src(16) | bf16(w)<<16. One edge per thread, global cursor.
__global__ __launch_bounds__(256) void bin_kernel(
    const int* __restrict__ ei, const float* __restrict__ ew,
    int* __restrict__ cur, unsigned* __restrict__ epk)
{
    const int e = blockIdx.x * 256 + threadIdx.x;    // exact grid
    int src = ei[e];
    int dst = ei[EE + e];
    unsigned w = f2bf(ew[e]);
    int pos = atomicAdd(&cur[dst], 1);               // device-scope
    epk[pos] = (unsigned)src | (w << 16);
}

// ---------- aggregation (fused relu epilogue), quarter lanes, fp8 Z ------
// Wave per dst node. s = lane&15 -> feature quad (4 fp8 = uint, 4B);
// q = lane>>4 -> edge phase. One Z row = 64B = ONE cache line. UNCHANGED.
template <bool FP32OUT>
__global__ __launch_bounds__(256) void aggregate_kernel(
    const unsigned* __restrict__ Z1,        // Z8 rows as 16 x uint
    const uint2* __restrict__ Y4,           // Yb rows as 16 x uint2
    const int* __restrict__ beg, const int* __restrict__ endo,
    const unsigned* __restrict__ epk, void* __restrict__ Hout)
{
    const int lane = threadIdx.x & 63;
    const int node = blockIdx.x * 4 + (threadIdx.x >> 6);
    if (node >= NN) return;
    const int s = lane & 15;
    const int q = lane >> 4;

    const int b = beg[node];
    const int e = endo[node];
    const uint2 y4 = Y4[node * 16 + s];

    float a0 = 0.f, a1 = 0.f, a2 = 0.f, a3 = 0.f;
    int i = b;
    for (; i + 16 <= e; i += 16) {          // 4 quad-slots = 16 edges
        unsigned pA = epk[i + q];
        unsigned pB = epk[i + 4 + q];
        unsigned pC = epk[i + 8 + q];
        unsigned pD = epk[i + 12 + q];
        unsigned zA = Z1[(pA & 0xFFFF) * 16 + s];
        unsigned zB = Z1[(pB & 0xFFFF) * 16 + s];
        unsigned zC = Z1[(pC & 0xFFFF) * 16 + s];
        unsigned zD = Z1[(pD & 0xFFFF) * 16 + s];
        float wA = __uint_as_float(pA & 0xFFFF0000u);
        float wB = __uint_as_float(pB & 0xFFFF0000u);
        float wC = __uint_as_float(pC & 0xFFFF0000u);
        float wD = __uint_as_float(pD & 0xFFFF0000u);
        a0 = fmaf(wA, __builtin_amdgcn_cvt_f32_fp8(zA, 0), a0);
        a1 = fmaf(wA, __builtin_amdgcn_cvt_f32_fp8(zA, 1), a1);
        a2 = fmaf(wA, __builtin_amdgcn_cvt_f32_fp8(zA, 2), a2);
        a3 = fmaf(wA, __builtin_amdgcn_cvt_f32_fp8(zA, 3), a3);
        a0 = fmaf(wB, __builtin_amdgcn_cvt_f32_fp8(zB, 0), a0);
        a1 = fmaf(wB, __builtin_amdgcn_cvt_f32_fp8(zB, 1), a1);
        a2 = fmaf(wB, __builtin_amdgcn_cvt_f32_fp8(zB, 2), a2);
        a3 = fmaf(wB, __builtin_amdgcn_cvt_f32_fp8(zB, 3), a3);
        a0 = fmaf(wC, __builtin_amdgcn_cvt_f32_fp8(zC, 0), a0);
        a1 = fmaf(wC, __builtin_amdgcn_cvt_f32_fp8(zC, 1), a1);
        a2 = fmaf(wC, __builtin_amdgcn_cvt_f32_fp8(zC, 2), a2);
        a3 = fmaf(wC, __builtin_amdgcn_cvt_f32_fp8(zC, 3), a3);
        a0 = fmaf(wD, __builtin_amdgcn_cvt_f32_fp8(zD, 0), a0);
        a1 = fmaf(wD, __builtin_amdgcn_cvt_f32_fp8(zD, 1), a1);
        a2 = fmaf(wD, __builtin_amdgcn_cvt_f32_fp8(zD, 2), a2);
        a3 = fmaf(wD, __builtin_amdgcn_cvt_f32_fp8(zD, 3), a3);
    }
    for (; i < e; i += 4) {                 // tail: predicated quad-slot
        int ee = i + q;
        unsigned p = (ee < e) ? epk[ee] : 0u;   // w=+0 kills the lane
        unsigned z = Z1[(p & 0xFFFF) * 16 + s];
        float w = __uint_as_float(p & 0xFFFF0000u);
        a0 = fmaf(w, __builtin_amdgcn_cvt_f32_fp8(z, 0), a0);
        a1 = fmaf(w, __builtin_amdgcn_cvt_f32_fp8(z, 1), a1);
        a2 = fmaf(w, __builtin_amdgcn_cvt_f32_fp8(z, 2), a2);
        a3 = fmaf(w, __builtin_amdgcn_cvt_f32_fp8(z, 3), a3);
    }

    a0 += __shfl_xor(a0, 16); a0 += __shfl_xor(a0, 32);
    a1 += __shfl_xor(a1, 16); a1 += __shfl_xor(a1, 32);
    a2 += __shfl_xor(a2, 16); a2 += __shfl_xor(a2, 32);
    a3 += __shfl_xor(a3, 16); a3 += __shfl_xor(a3, 32);

    if (q == 0) {
        float r0 = fmaxf(a0 + bflo(y4.x), 0.0f);
        float r1 = fmaxf(a1 + bfhi(y4.x), 0.0f);
        float r2 = fmaxf(a2 + bflo(y4.y), 0.0f);
        float r3 = fmaxf(a3 + bfhi(y4.y), 0.0f);
        if (FP32OUT) {
            ((float4*)Hout)[node * 16 + s] = make_float4(r0, r1, r2, r3);
        } else {
            uint2 o;
            o.x = (unsigned)f2bf(r0) | ((unsigned)f2bf(r1) << 16);
            o.y = (unsigned)f2bf(r2) | ((unsigned)f2bf(r3) << 16);
            ((uint2*)Hout)[node * 16 + s] = o;
        }
    }
}

// ---------- layer-2 transform (bf16 input) ----------
__global__ __launch_bounds__(256) void transform2_kernel(
    const unsigned short* __restrict__ xin,
    const float* __restrict__ Wrel, const float* __restrict__ Wroot,
    const float* __restrict__ bias,
    unsigned char* __restrict__ Z8, unsigned short* __restrict__ Yb)
{
    __shared__ unsigned short Xs[64 * XS_STR];
    __shared__ unsigned short Ws[128 * WS_STR];
    transform_body<unsigned short>(blockIdx.x, threadIdx.x, xin, Wrel, Wroot,
                                   bias, Z8, Yb, Xs, Ws);
}

extern "C" void kernel_launch(void* const* d_in, const int* in_sizes, int n_in,
                              void* d_out, int out_size, void* d_ws, size_t ws_size,
                              hipStream_t stream)
{
    const float* x     = (const float*)d_in[0];
    const int*   ei    = (const int*)  d_in[1];
    const float* ew    = (const float*)d_in[2];
    const float* Wrel1 = (const float*)d_in[3];
    const float* brel1 = (const float*)d_in[4];
    const float* Wroot1= (const float*)d_in[5];
    const float* Wrel2 = (const float*)d_in[6];
    const float* brel2 = (const float*)d_in[7];
    const float* Wroot2= (const float*)d_in[8];

    float* out = (float*)d_out;                 // final output only

    const size_t ND = (size_t)NN * DD;          // 3.2e6 elements
    // ALL regions disjoint. Total ~23.3 MB (ws = 256 MiB).
    char* w = (char*)d_ws;
    unsigned char*  Z8 = (unsigned char*)w;                     //  3.20 MB
    unsigned short* Yb = (unsigned short*)(w + ND);             //  6.40 MB
    unsigned short* Hb = (unsigned short*)(w + ND * 3);         //  6.40 MB
    unsigned* epk = (unsigned*)(w + ND * 5);                    //  6.40 MB dense
    int* cnt  = (int*)(w + ND * 5 + (size_t)EE * 4);            //  0.20 MB
    int* beg  = cnt + NN;                                       //  0.20 MB
    int* endo = beg + NN;                                       //  0.20 MB
    int* cur  = endo + NN;                                      //  0.20 MB
    int* btot = cur + NN;                                       //  784 B

    const int tb = (NN + 63) / 64;              // 782 transform blocks
    const int ab = (NN + 3) / 4;                // 12500 aggregate blocks

    // ---- build 0: zero node histogram ----
    zero_kernel<<<NSB, 256, 0, stream>>>(cnt);
    // ---- fused: node-histogram chunks + layer-1 transform ----
    hist_t1_kernel<<<NC + tb, 256, 0, stream>>>(ei, cnt, x, Wrel1, Wroot1,
                                                brel1, Z8, Yb);
    // ---- scan: per-node exclusive offsets (beg/endo/cur) ----
    scan_a<<<NSB, 256, 0, stream>>>(cnt, btot);
    scan_c<<<NSB, 256, 0, stream>>>(cnt, btot, beg, endo, cur);
    // ---- place records at final sorted positions (dense epk) ----
    bin_kernel<<<EE / 256, 256, 0, stream>>>(ei, ew, cur, epk);

    // ---- layer 1 aggregate ----
    aggregate_kernel<false><<<ab, 256, 0, stream>>>(
        (const unsigned*)Z8, (const uint2*)Yb, beg, endo, epk, Hb);

    // ---- layer 2 ----
    transform2_kernel<<<tb, 256, 0, stream>>>(Hb, Wrel2, Wroot2, brel2, Z8, Yb);
    aggregate_kernel<true><<<ab, 256, 0, stream>>>(
        (const unsigned*)Z8, (const uint2*)Yb, beg, endo, epk, out);
}